// Round 13
// baseline (149.402 us; speedup 1.0000x reference)
//
#include <hip/hip_runtime.h>

// SSM: h_t = A h_{t-1} + B x_t ; y_t = C h_t + D x_t
// BATCH=128, T=2048, N=64, f32.
// Round 11: chunked DUAL form. L=8-step chunks; per chunk y is a pure GEMM:
//   y_s = C A^{s+1} S + sum_{i<=s} G_{s-i} x_i + D x_s,  G_m = C A^m B
// Y^T(128b x 512to) = X^T(128 x 512) @ TtT(512..640 K) with K-ext for S(hi/lo).
// Chunk-final states f = W @ x_vec (GEMM).  No serial recurrence anywhere
// except the tiny f32 boundary scans (proven rounds 9/10).
// TtT stored n-major [n=512][k=640] bf16 so B-op frags are contiguous 16B.

#define T_SEQ 2048

typedef __bf16 bf16x8 __attribute__((ext_vector_type(8)));
typedef float f32x4 __attribute__((ext_vector_type(4)));
typedef float f32x16 __attribute__((ext_vector_type(16)));

#define MFMA32(a, b, c) __builtin_amdgcn_mfma_f32_32x32x16_bf16(a, b, c, 0, 0, 0)
#define MFMA16(a, b, c) __builtin_amdgcn_mfma_f32_16x16x32_bf16(a, b, c, 0, 0, 0)

typedef __bf16 (*ldsmat)[72];

__device__ __forceinline__ float bcast(float v, int l) {
    return __int_as_float(__builtin_amdgcn_readlane(__float_as_int(v), l));
}
__device__ __forceinline__ f32x16 z16() {
    f32x16 z;
#pragma unroll
    for (int e = 0; e < 16; ++e) z[e] = 0.f;
    return z;
}
__device__ __forceinline__ void split8(f32x4 a, f32x4 b, bf16x8& hi, bf16x8& lo) {
#pragma unroll
    for (int i = 0; i < 4; ++i) {
        float v = a[i]; __bf16 h = (__bf16)v; hi[i] = h; lo[i] = (__bf16)(v - (float)h);
        v = b[i]; h = (__bf16)v; hi[4 + i] = h; lo[4 + i] = (__bf16)(v - (float)h);
    }
}

// ---------------- k_zero: zero TtT (655,360 B) ----------------------------
__global__ __launch_bounds__(256) void k_zero(float* __restrict__ p) {
    int i = blockIdx.x * 256 + threadIdx.x;     // 160*256 = 40960 f32x4 = 640KB
    ((f32x4*)p)[i] = (f32x4){0.f, 0.f, 0.f, 0.f};
}

// ---------------- prep helpers (16x16x32 split-MFMA on 64x64 LDS mats) -----
// mm_core: accs = X @ Ystored^T (3-mult split).
// accs[mt][r] = D[mt*16+fq*4+r][w*16+fr].  (Ystored symmetric => X@Y.)
__device__ __forceinline__ void mm_core(int w, int fr, int fq,
        const __bf16 (*Xh)[72], const __bf16 (*Xl)[72],
        const __bf16 (*Yh)[72], const __bf16 (*Yl)[72], f32x4* accs) {
#pragma unroll
    for (int mt = 0; mt < 4; ++mt) {
        f32x4 acc = {0.f, 0.f, 0.f, 0.f};
#pragma unroll
        for (int kk = 0; kk < 2; ++kk) {
            bf16x8 xh = *(const bf16x8*)&Xh[mt * 16 + fr][fq * 8 + kk * 32];
            bf16x8 xl = *(const bf16x8*)&Xl[mt * 16 + fr][fq * 8 + kk * 32];
            bf16x8 yh = *(const bf16x8*)&Yh[w * 16 + fr][fq * 8 + kk * 32];
            bf16x8 yl = *(const bf16x8*)&Yl[w * 16 + fr][fq * 8 + kk * 32];
            acc = MFMA16(xh, yh, acc);
            acc = MFMA16(xh, yl, acc);
            acc = MFMA16(xl, yh, acc);
        }
        accs[mt] = acc;
    }
}
__device__ __forceinline__ void acc_to_lds(int w, int fr, int fq,
        const f32x4* accs, __bf16 (*Dh)[72], __bf16 (*Dl)[72]) {
#pragma unroll
    for (int mt = 0; mt < 4; ++mt)
#pragma unroll
        for (int r = 0; r < 4; ++r) {
            float v = accs[mt][r]; __bf16 h = (__bf16)v;
            Dh[mt * 16 + fq * 4 + r][w * 16 + fr] = h;
            Dl[mt * 16 + fq * 4 + r][w * 16 + fr] = (__bf16)(v - (float)h);
        }
}
__device__ __forceinline__ void stage_split(const float* __restrict__ M, int tid,
        __bf16 (*Mh)[72], __bf16 (*Ml)[72]) {
    for (int i = tid; i < 4096; i += 256) {
        float v = M[i]; __bf16 h = (__bf16)v;
        Mh[i >> 6][i & 63] = h; Ml[i >> 6][i & 63] = (__bf16)(v - (float)h);
    }
}
__device__ __forceinline__ void stage_split_T(const float* __restrict__ M, int tid,
        __bf16 (*Mh)[72], __bf16 (*Ml)[72]) {
    for (int i = tid; i < 4096; i += 256) {
        int k = i >> 6, d = i & 63;
        float v = M[i]; __bf16 h = (__bf16)v;
        Mh[d][k] = h; Ml[d][k] = (__bf16)(v - (float)h);
    }
}

// ---------------- k_prep: build TtT, WtT, P8, P128 -------------------------
// block 0:   G0 = C@B + D -> 8 diag blocks; WtT pos 7 = B.
// block j=1..8: A^j (chain of xA mults); E_{j-1} = C@A^j -> TtT k=512/576 cols;
//            j<=7: G_j = E@B -> blocks (i+j, i); W = A^j@B -> WtT pos 7-j.
// block 9:   squarings -> P8 = A^8 f32, P128 = A^128 f32.
__global__ __launch_bounds__(256) void k_prep(const float* __restrict__ A,
        const float* __restrict__ B, const float* __restrict__ C,
        const float* __restrict__ Dm, float* __restrict__ P8,
        float* __restrict__ P128, __bf16* __restrict__ TtT,
        __bf16* __restrict__ WtT) {
    __shared__ __align__(16) __bf16 U1h[64][72], U1l[64][72];
    __shared__ __align__(16) __bf16 U2h[64][72], U2l[64][72];
    __shared__ __align__(16) __bf16 U3h[64][72], U3l[64][72];
    int tid = threadIdx.x;
    int w = tid >> 6, lane = tid & 63, fr = lane & 15, fq = lane >> 4;
    int bid = blockIdx.x;
    f32x4 accs[4];

    if (bid == 9) {
        stage_split(A, tid, U1h, U1l);
        __syncthreads();
        ldsmat curh = U1h, curl = U1l, oth = U2h, otl = U2l;
        for (int sq = 0; sq < 7; ++sq) {        // cur -> cur^2
            mm_core(w, fr, fq, curh, curl, curh, curl, accs);
            __syncthreads();
            acc_to_lds(w, fr, fq, accs, oth, otl);
            __syncthreads();
            { ldsmat t = curh; curh = oth; oth = t;
              t = curl; curl = otl; otl = t; }
            if (sq == 2)
                for (int i = tid; i < 4096; i += 256)
                    P8[i] = (float)curh[i >> 6][i & 63] + (float)curl[i >> 6][i & 63];
        }
        for (int i = tid; i < 4096; i += 256)
            P128[i] = (float)curh[i >> 6][i & 63] + (float)curl[i >> 6][i & 63];
        return;
    }
    if (bid == 0) {
        stage_split(C, tid, U1h, U1l);
        stage_split_T(B, tid, U2h, U2l);
        __syncthreads();
        mm_core(w, fr, fq, U1h, U1l, U2h, U2l, accs);   // C @ B
#pragma unroll
        for (int mt = 0; mt < 4; ++mt)
#pragma unroll
            for (int r = 0; r < 4; ++r) {
                int row = mt * 16 + fq * 4 + r, col = w * 16 + fr;
                float v = accs[mt][r] + Dm[row * 64 + col];
                __bf16 hv = (__bf16)v;
                for (int s = 0; s < 8; ++s)
                    TtT[(long)(s * 64 + row) * 640 + s * 64 + col] = hv;
            }
        for (int i = tid; i < 4096; i += 256) {
            int o = i >> 6, d = i & 63;
            WtT[(long)o * 512 + 7 * 64 + d] = (__bf16)B[i];  // W_7 = A^0 B
        }
        return;
    }
    // bid = j in 1..8
    int j = bid;
    stage_split(A, tid, U1h, U1l);
    stage_split(A, tid, U3h, U3l);
    __syncthreads();
    ldsmat curh = U1h, curl = U1l, oth = U2h, otl = U2l;
    for (int s = 1; s < j; ++s) {               // cur = cur @ A
        mm_core(w, fr, fq, curh, curl, U3h, U3l, accs);
        __syncthreads();
        acc_to_lds(w, fr, fq, accs, oth, otl);
        __syncthreads();
        { ldsmat t = curh; curh = oth; oth = t;
          t = curl; curl = otl; otl = t; }
    }
    // E = C @ A^j
    stage_split(C, tid, oth, otl);
    __syncthreads();
    mm_core(w, fr, fq, oth, otl, curh, curl, accs);
    __syncthreads();
#pragma unroll
    for (int mt = 0; mt < 4; ++mt)
#pragma unroll
        for (int r = 0; r < 4; ++r) {
            int row = mt * 16 + fq * 4 + r, col = w * 16 + fr;
            float v = accs[mt][r]; __bf16 h = (__bf16)v;
            TtT[(long)((j - 1) * 64 + row) * 640 + 512 + col] = h;   // E for S_hi
            TtT[(long)((j - 1) * 64 + row) * 640 + 576 + col] = h;   // E for S_lo
            U3h[row][col] = h; U3l[row][col] = (__bf16)(v - (float)h);
        }
    __syncthreads();
    if (j <= 7) {
        stage_split_T(B, tid, oth, otl);
        __syncthreads();
        mm_core(w, fr, fq, U3h, U3l, oth, otl, accs);    // G_j = E @ B
#pragma unroll
        for (int mt = 0; mt < 4; ++mt)
#pragma unroll
            for (int r = 0; r < 4; ++r) {
                int row = mt * 16 + fq * 4 + r, col = w * 16 + fr;
                __bf16 hv = (__bf16)accs[mt][r];
                for (int i2 = 0; i2 + j < 8; ++i2)
                    TtT[(long)((i2 + j) * 64 + row) * 640 + i2 * 64 + col] = hv;
            }
        mm_core(w, fr, fq, curh, curl, oth, otl, accs);  // W = A^j @ B
#pragma unroll
        for (int mt = 0; mt < 4; ++mt)
#pragma unroll
            for (int r = 0; r < 4; ++r) {
                int row = mt * 16 + fq * 4 + r, col = w * 16 + fr;
                WtT[(long)row * 512 + (7 - j) * 64 + col] = (__bf16)accs[mt][r];
            }
    }
}

// ---------------- k_gemm1: f_c = W @ x_vec (chunk-final local states) ------
__global__ __launch_bounds__(64) void k_gemm1(const float* __restrict__ x,
        const __bf16* __restrict__ WtT, float* __restrict__ fbuf) {
    __shared__ __bf16 LA[32][64][8];
    int lane = threadIdx.x;
    int c = blockIdx.x >> 2, bg = blockIdx.x & 3;
#pragma unroll 4
    for (int it = 0; it < 64; ++it) {
        int q = lane + 64 * it;
        int dq = (q & 15) * 4, b = (q >> 4) & 31, t2 = q >> 9;
        f32x4 v = *(const f32x4*)(x + ((long)(bg * 32 + b) * T_SEQ + c * 8 + t2) * 64 + dq);
        int k = t2 * 64 + dq;
        __bf16* d = &LA[k >> 4][((k >> 3) & 1) * 32 + b][k & 7];
        d[0] = (__bf16)v[0]; d[1] = (__bf16)v[1];
        d[2] = (__bf16)v[2]; d[3] = (__bf16)v[3];
    }
    __syncthreads();
    int bcol = lane & 31, hl = lane >> 5;
    const __bf16* wb0 = WtT + (long)bcol * 512 + 8 * hl;
    f32x16 a0 = z16(), a1 = z16();
    for (int kt = 0; kt < 32; ++kt) {
        bf16x8 a = *(const bf16x8*)&LA[kt][lane][0];
        a0 = MFMA32(a, *(const bf16x8*)(wb0 + kt * 16), a0);
        a1 = MFMA32(a, *(const bf16x8*)(wb0 + 32 * 512 + kt * 16), a1);
    }
    float* fp = fbuf + ((long)c * 128 + bg * 32) * 64;
#pragma unroll
    for (int r = 0; r < 16; ++r) {
        int row = (r & 3) + 8 * (r >> 2) + 4 * hl;
        fp[(long)row * 64 + bcol] = a0[r];
        fp[(long)row * 64 + 32 + bcol] = a1[r];
    }
}

// ---------------- boundary scans (round-9/10 proven) -----------------------
__global__ __launch_bounds__(256) void k_bound1(const float* __restrict__ P,
        const float* __restrict__ fbuf, float* __restrict__ Fsup, int nper) {
    int wid = blockIdx.x * 4 + (threadIdx.x >> 6);
    int lane = threadIdx.x & 63;
    int s = wid >> 7, batch = wid & 127;
    float Pr[64];
    const f32x4* P4 = (const f32x4*)(P + lane * 64);
#pragma unroll
    for (int qq = 0; qq < 16; ++qq) {
        f32x4 v = P4[qq];
        Pr[qq*4] = v[0]; Pr[qq*4+1] = v[1]; Pr[qq*4+2] = v[2]; Pr[qq*4+3] = v[3];
    }
    float S = 0.f;
    for (int i = 0; i < nper; ++i) {
        int c = s * nper + i;
        float fv = fbuf[((long)c * 128 + batch) * 64 + lane];
        float a0 = fv, a1 = 0.f;
#pragma unroll
        for (int m = 0; m < 64; m += 2) {
            a0 = fmaf(Pr[m],     bcast(S, m),     a0);
            a1 = fmaf(Pr[m + 1], bcast(S, m + 1), a1);
        }
        S = a0 + a1;
    }
    Fsup[((long)s * 128 + batch) * 64 + lane] = S;
}

__global__ __launch_bounds__(256) void k_bsuper(const float* __restrict__ P,
        float* __restrict__ Fsup, int nsup) {
    int batch = blockIdx.x * 4 + (threadIdx.x >> 6);
    int lane = threadIdx.x & 63;
    float Pr[64];
    const f32x4* P4 = (const f32x4*)(P + lane * 64);
#pragma unroll
    for (int qq = 0; qq < 16; ++qq) {
        f32x4 v = P4[qq];
        Pr[qq*4] = v[0]; Pr[qq*4+1] = v[1]; Pr[qq*4+2] = v[2]; Pr[qq*4+3] = v[3];
    }
    float E = 0.f;
    for (int s = 0; s < nsup; ++s) {
        long idx = ((long)s * 128 + batch) * 64 + lane;
        float tmp = Fsup[idx];
        Fsup[idx] = E;
        float a0 = tmp, a1 = 0.f;
#pragma unroll
        for (int m = 0; m < 64; m += 2) {
            a0 = fmaf(Pr[m],     bcast(E, m),     a0);
            a1 = fmaf(Pr[m + 1], bcast(E, m + 1), a1);
        }
        E = a0 + a1;
    }
}

__global__ __launch_bounds__(256) void k_bound2(const float* __restrict__ P,
        const float* __restrict__ Fsup, float* __restrict__ fbuf, int nper) {
    int wid = blockIdx.x * 4 + (threadIdx.x >> 6);
    int lane = threadIdx.x & 63;
    int s = wid >> 7, batch = wid & 127;
    float Pr[64];
    const f32x4* P4 = (const f32x4*)(P + lane * 64);
#pragma unroll
    for (int qq = 0; qq < 16; ++qq) {
        f32x4 v = P4[qq];
        Pr[qq*4] = v[0]; Pr[qq*4+1] = v[1]; Pr[qq*4+2] = v[2]; Pr[qq*4+3] = v[3];
    }
    float S = Fsup[((long)s * 128 + batch) * 64 + lane];
    for (int i = 0; i < nper; ++i) {
        int c = s * nper + i;
        long idx = ((long)c * 128 + batch) * 64 + lane;
        float tmp = fbuf[idx];
        fbuf[idx] = S;                 // entry state of chunk c
        float a0 = tmp, a1 = 0.f;
#pragma unroll
        for (int m = 0; m < 64; m += 2) {
            a0 = fmaf(Pr[m],     bcast(S, m),     a0);
            a1 = fmaf(Pr[m + 1], bcast(S, m + 1), a1);
        }
        S = a0 + a1;
    }
}

// ---------------- k_gemm2: Y^T = X^T @ TtT  (+ S-extension) ----------------
// WG = (chunk c, batch-group bg of 32). 4 waves; wave wq owns N-cols
// [wq*128, wq*128+128) = 4 tiles of 32; wq = (w + c) & 3 balances SIMDs.
// Triangular skip: tile at step s needs x-K < 64(s+1); S-K (kt 32..39) always.
__global__ __launch_bounds__(256) void k_gemm2(const float* __restrict__ x,
        const float* __restrict__ Sbuf, const __bf16* __restrict__ TtT,
        float* __restrict__ y) {
    __shared__ __bf16 LA[40][64][8];
    int tid = threadIdx.x;
    int c = blockIdx.x >> 2, bg = blockIdx.x & 3;
    {   // stage X (8 t x 64 d x 32 b), A-frag order
        int dq = (tid & 15) * 4;
        int b0 = tid >> 4;
#pragma unroll
        for (int t2 = 0; t2 < 8; ++t2)
#pragma unroll
            for (int rep = 0; rep < 2; ++rep) {
                int b = b0 + rep * 16;
                f32x4 v = *(const f32x4*)(x + ((long)(bg * 32 + b) * T_SEQ + c * 8 + t2) * 64 + dq);
                int k = t2 * 64 + dq;
                __bf16* d = &LA[k >> 4][((k >> 3) & 1) * 32 + b][k & 7];
                d[0] = (__bf16)v[0]; d[1] = (__bf16)v[1];
                d[2] = (__bf16)v[2]; d[3] = (__bf16)v[3];
            }
    }
    {   // stage S hi/lo (k 512..639)
        int b = tid >> 3, d0 = (tid & 7) * 8;
        const float* sp = Sbuf + ((long)c * 128 + bg * 32 + b) * 64 + d0;
        f32x4 s0 = *(const f32x4*)sp, s1 = *(const f32x4*)(sp + 4);
        bf16x8 hi, lo;
        split8(s0, s1, hi, lo);
        int kh = 512 + d0, kl = 576 + d0;
        *(bf16x8*)&LA[kh >> 4][((kh >> 3) & 1) * 32 + b][0] = hi;
        *(bf16x8*)&LA[kl >> 4][((kl >> 3) & 1) * 32 + b][0] = lo;
    }
    __syncthreads();
    int w = tid >> 6, lane = tid & 63;
    int bcol = lane & 31, hl = lane >> 5;
    int wq = (w + c) & 3;
    const __bf16* tb0 = TtT + (long)(wq * 128 + bcol) * 640 + 8 * hl;
    f32x16 acc[4] = {z16(), z16(), z16(), z16()};
    int k1 = 8 * wq + 4, k2 = k1 + 4;
    int kt = 0;
    for (; kt < k1; ++kt) {             // all 4 tiles active
        bf16x8 a = *(const bf16x8*)&LA[kt][lane][0];
        acc[0] = MFMA32(a, *(const bf16x8*)(tb0 + (long)kt * 16), acc[0]);
        acc[1] = MFMA32(a, *(const bf16x8*)(tb0 + 32l * 640 + kt * 16), acc[1]);
        acc[2] = MFMA32(a, *(const bf16x8*)(tb0 + 64l * 640 + kt * 16), acc[2]);
        acc[3] = MFMA32(a, *(const bf16x8*)(tb0 + 96l * 640 + kt * 16), acc[3]);
    }
    for (; kt < k2; ++kt) {             // only second-step tiles (j=2,3)
        bf16x8 a = *(const bf16x8*)&LA[kt][lane][0];
        acc[2] = MFMA32(a, *(const bf16x8*)(tb0 + 64l * 640 + kt * 16), acc[2]);
        acc[3] = MFMA32(a, *(const bf16x8*)(tb0 + 96l * 640 + kt * 16), acc[3]);
    }
    for (kt = 32; kt < 40; ++kt) {      // S extension, all tiles
        bf16x8 a = *(const bf16x8*)&LA[kt][lane][0];
        acc[0] = MFMA32(a, *(const bf16x8*)(tb0 + (long)kt * 16), acc[0]);
        acc[1] = MFMA32(a, *(const bf16x8*)(tb0 + 32l * 640 + kt * 16), acc[1]);
        acc[2] = MFMA32(a, *(const bf16x8*)(tb0 + 64l * 640 + kt * 16), acc[2]);
        acc[3] = MFMA32(a, *(const bf16x8*)(tb0 + 96l * 640 + kt * 16), acc[3]);
    }
    // store: coalesced (lanes 0..31 -> 32 consecutive o of one batch row)
    long ybase = (long)(bg * 32) * 131072 + (long)c * 8 * 64;
#pragma unroll
    for (int j = 0; j < 4; ++j) {
        int s = 2 * wq + (j >> 1), ob = 32 * (j & 1);
        float* yp = y + ybase + s * 64 + ob + bcol;
#pragma unroll
        for (int r = 0; r < 16; ++r) {
            int row = (r & 3) + 8 * (r >> 2) + 4 * hl;
            yp[(long)row * 131072] = acc[j][r];
        }
    }
}

extern "C" void kernel_launch(void* const* d_in, const int* in_sizes, int n_in,
                              void* d_out, int out_size, void* d_ws, size_t ws_size,
                              hipStream_t stream) {
    const float* x = (const float*)d_in[0];
    const float* A = (const float*)d_in[1];
    const float* B = (const float*)d_in[2];
    const float* C = (const float*)d_in[3];
    const float* Dm = (const float*)d_in[4];
    float* y = (float*)d_out;
    char* ws = (char*)d_ws;

    __bf16* TtT  = (__bf16*)(ws);                 // 512*640*2 = 655,360
    __bf16* WtT  = (__bf16*)(ws + 655360);        // 64*512*2 = 65,536
    float*  P8   = (float*)(ws + 720896);         // 16,384
    float*  P128 = (float*)(ws + 737280);         // 16,384
    float*  Fsup = (float*)(ws + 753664);         // 16*128*64*4 = 524,288
    float*  fbuf = (float*)(ws + 1277952);        // 256*128*64*4 = 8,388,608
    // total 9,666,560 B (ws >= 42.6 MB confirmed by round-10 packed run)

    k_zero<<<160, 256, 0, stream>>>((float*)TtT);
    k_prep<<<10, 256, 0, stream>>>(A, B, C, Dm, P8, P128, TtT, WtT);
    k_gemm1<<<1024, 64, 0, stream>>>(x, WtT, fbuf);
    k_bound1<<<512, 256, 0, stream>>>(P8, fbuf, Fsup, 16);
    k_bsuper<<<32, 256, 0, stream>>>(P128, Fsup, 16);
    k_bound2<<<512, 256, 0, stream>>>(P8, Fsup, fbuf, 16);
    k_gemm2<<<1024, 256, 0, stream>>>(x, fbuf, TtT, y);
}

// Round 15
// 133.243 us; speedup vs baseline: 1.1213x; 1.1213x over previous
//
#include <hip/hip_runtime.h>

// SSM: h_t = A h_{t-1} + B x_t ; y_t = C h_t + D x_t
// BATCH=128, T=2048, N=64, f32.
// Chunked DUAL form (round 11/13). L=8-step chunks; per chunk:
//   Y^T(128b x 512to) = X^T(128 x 640K incl S-ext) @ T  (block-lower-tri Toeplitz)
//   f = W @ x_vec (chunk-final states); tiny f32 boundary scans in between.
// Round 14: tables stored PRE-FRAGMENTED in B-operand order:
//   Tfrag[ntile][kt][lane][8]  (lane = ((k>>3)&1)*32 + (n&31))
// so a wave's table load = one coalesced 1024B L2 read. Round-13's n-major
// [n][640] layout made every fragment load a 64-line scatter (1280B stride)
// -> L1 serialization, MfmaUtil 7%, 72us. Only the addressing changed.

#define T_SEQ 2048

typedef __bf16 bf16x8 __attribute__((ext_vector_type(8)));
typedef float f32x4 __attribute__((ext_vector_type(4)));
typedef float f32x16 __attribute__((ext_vector_type(16)));

#define MFMA32(a, b, c) __builtin_amdgcn_mfma_f32_32x32x16_bf16(a, b, c, 0, 0, 0)
#define MFMA16(a, b, c) __builtin_amdgcn_mfma_f32_16x16x32_bf16(a, b, c, 0, 0, 0)

// B-operand fragment index: element (k, n) of the 512x640 table T.
//   ntile=n>>5, kt=k>>4, lane=((k>>3)&1)*32 + (n&31), e=k&7
#define TIDX(k, n) (((((long)((n) >> 5) * 40 + ((k) >> 4)) * 64 + \
                      (((k) >> 3) & 1) * 32 + ((n) & 31)) << 3) + ((k) & 7))
// Same for the 64x512 W table (32 kt):
#define WIDX(k, o) (((((long)((o) >> 5) * 32 + ((k) >> 4)) * 64 + \
                      (((k) >> 3) & 1) * 32 + ((o) & 31)) << 3) + ((k) & 7))

typedef __bf16 (*ldsmat)[72];

__device__ __forceinline__ float bcast(float v, int l) {
    return __int_as_float(__builtin_amdgcn_readlane(__float_as_int(v), l));
}
__device__ __forceinline__ f32x16 z16() {
    f32x16 z;
#pragma unroll
    for (int e = 0; e < 16; ++e) z[e] = 0.f;
    return z;
}
__device__ __forceinline__ void split8(f32x4 a, f32x4 b, bf16x8& hi, bf16x8& lo) {
#pragma unroll
    for (int i = 0; i < 4; ++i) {
        float v = a[i]; __bf16 h = (__bf16)v; hi[i] = h; lo[i] = (__bf16)(v - (float)h);
        v = b[i]; h = (__bf16)v; hi[4 + i] = h; lo[4 + i] = (__bf16)(v - (float)h);
    }
}

// ---------------- k_zero: zero Tfrag (655,360 B) ---------------------------
__global__ __launch_bounds__(256) void k_zero(float* __restrict__ p) {
    int i = blockIdx.x * 256 + threadIdx.x;
    ((f32x4*)p)[i] = (f32x4){0.f, 0.f, 0.f, 0.f};
}

// ---------------- prep helpers (16x16x32 split-MFMA on 64x64 LDS mats) -----
__device__ __forceinline__ void mm_core(int w, int fr, int fq,
        const __bf16 (*Xh)[72], const __bf16 (*Xl)[72],
        const __bf16 (*Yh)[72], const __bf16 (*Yl)[72], f32x4* accs) {
#pragma unroll
    for (int mt = 0; mt < 4; ++mt) {
        f32x4 acc = {0.f, 0.f, 0.f, 0.f};
#pragma unroll
        for (int kk = 0; kk < 2; ++kk) {
            bf16x8 xh = *(const bf16x8*)&Xh[mt * 16 + fr][fq * 8 + kk * 32];
            bf16x8 xl = *(const bf16x8*)&Xl[mt * 16 + fr][fq * 8 + kk * 32];
            bf16x8 yh = *(const bf16x8*)&Yh[w * 16 + fr][fq * 8 + kk * 32];
            bf16x8 yl = *(const bf16x8*)&Yl[w * 16 + fr][fq * 8 + kk * 32];
            acc = MFMA16(xh, yh, acc);
            acc = MFMA16(xh, yl, acc);
            acc = MFMA16(xl, yh, acc);
        }
        accs[mt] = acc;
    }
}
__device__ __forceinline__ void acc_to_lds(int w, int fr, int fq,
        const f32x4* accs, __bf16 (*Dh)[72], __bf16 (*Dl)[72]) {
#pragma unroll
    for (int mt = 0; mt < 4; ++mt)
#pragma unroll
        for (int r = 0; r < 4; ++r) {
            float v = accs[mt][r]; __bf16 h = (__bf16)v;
            Dh[mt * 16 + fq * 4 + r][w * 16 + fr] = h;
            Dl[mt * 16 + fq * 4 + r][w * 16 + fr] = (__bf16)(v - (float)h);
        }
}
__device__ __forceinline__ void stage_split(const float* __restrict__ M, int tid,
        __bf16 (*Mh)[72], __bf16 (*Ml)[72]) {
    for (int i = tid; i < 4096; i += 256) {
        float v = M[i]; __bf16 h = (__bf16)v;
        Mh[i >> 6][i & 63] = h; Ml[i >> 6][i & 63] = (__bf16)(v - (float)h);
    }
}
__device__ __forceinline__ void stage_split_T(const float* __restrict__ M, int tid,
        __bf16 (*Mh)[72], __bf16 (*Ml)[72]) {
    for (int i = tid; i < 4096; i += 256) {
        int k = i >> 6, d = i & 63;
        float v = M[i]; __bf16 h = (__bf16)v;
        Mh[d][k] = h; Ml[d][k] = (__bf16)(v - (float)h);
    }
}

// ---------------- k_prep: build Tfrag, Wfrag, P8, P128 ---------------------
// block 0:   G0 = C@B + D -> 8 diag blocks; Wfrag pos 7 = B.
// block j=1..8: A^j; E_{j-1}=C@A^j -> k=512/576 ext cols; j<=7: G_j=E@B ->
//            blocks (i+j, i); W=A^j@B -> Wfrag pos 7-j.
// block 9:   squarings -> P8 = A^8 f32, P128 = A^128 f32.
__global__ __launch_bounds__(256) void k_prep(const float* __restrict__ A,
        const float* __restrict__ B, const float* __restrict__ C,
        const float* __restrict__ Dm, float* __restrict__ P8,
        float* __restrict__ P128, __bf16* __restrict__ Tfrag,
        __bf16* __restrict__ Wfrag) {
    __shared__ __align__(16) __bf16 U1h[64][72], U1l[64][72];
    __shared__ __align__(16) __bf16 U2h[64][72], U2l[64][72];
    __shared__ __align__(16) __bf16 U3h[64][72], U3l[64][72];
    int tid = threadIdx.x;
    int w = tid >> 6, lane = tid & 63, fr = lane & 15, fq = lane >> 4;
    int bid = blockIdx.x;
    f32x4 accs[4];

    if (bid == 9) {
        stage_split(A, tid, U1h, U1l);
        __syncthreads();
        ldsmat curh = U1h, curl = U1l, oth = U2h, otl = U2l;
        for (int sq = 0; sq < 7; ++sq) {        // cur -> cur^2
            mm_core(w, fr, fq, curh, curl, curh, curl, accs);
            __syncthreads();
            acc_to_lds(w, fr, fq, accs, oth, otl);
            __syncthreads();
            { ldsmat t = curh; curh = oth; oth = t;
              t = curl; curl = otl; otl = t; }
            if (sq == 2)
                for (int i = tid; i < 4096; i += 256)
                    P8[i] = (float)curh[i >> 6][i & 63] + (float)curl[i >> 6][i & 63];
        }
        for (int i = tid; i < 4096; i += 256)
            P128[i] = (float)curh[i >> 6][i & 63] + (float)curl[i >> 6][i & 63];
        return;
    }
    if (bid == 0) {
        stage_split(C, tid, U1h, U1l);
        stage_split_T(B, tid, U2h, U2l);
        __syncthreads();
        mm_core(w, fr, fq, U1h, U1l, U2h, U2l, accs);   // C @ B
#pragma unroll
        for (int mt = 0; mt < 4; ++mt)
#pragma unroll
            for (int r = 0; r < 4; ++r) {
                int row = mt * 16 + fq * 4 + r, col = w * 16 + fr;
                float v = accs[mt][r] + Dm[row * 64 + col];
                __bf16 hv = (__bf16)v;
                for (int s = 0; s < 8; ++s)
                    Tfrag[TIDX(s * 64 + col, s * 64 + row)] = hv;
            }
        for (int i = tid; i < 4096; i += 256) {
            int o = i >> 6, d = i & 63;
            Wfrag[WIDX(7 * 64 + d, o)] = (__bf16)B[i];  // W_7 = A^0 B
        }
        return;
    }
    // bid = j in 1..8
    int j = bid;
    stage_split(A, tid, U1h, U1l);
    stage_split(A, tid, U3h, U3l);
    __syncthreads();
    ldsmat curh = U1h, curl = U1l, oth = U2h, otl = U2l;
    for (int s = 1; s < j; ++s) {               // cur = cur @ A
        mm_core(w, fr, fq, curh, curl, U3h, U3l, accs);
        __syncthreads();
        acc_to_lds(w, fr, fq, accs, oth, otl);
        __syncthreads();
        { ldsmat t = curh; curh = oth; oth = t;
          t = curl; curl = otl; otl = t; }
    }
    // E = C @ A^j
    stage_split(C, tid, oth, otl);
    __syncthreads();
    mm_core(w, fr, fq, oth, otl, curh, curl, accs);
    __syncthreads();
#pragma unroll
    for (int mt = 0; mt < 4; ++mt)
#pragma unroll
        for (int r = 0; r < 4; ++r) {
            int row = mt * 16 + fq * 4 + r, col = w * 16 + fr;
            float v = accs[mt][r]; __bf16 h = (__bf16)v;
            Tfrag[TIDX(512 + col, (j - 1) * 64 + row)] = h;   // E for S_hi
            Tfrag[TIDX(576 + col, (j - 1) * 64 + row)] = h;   // E for S_lo
            U3h[row][col] = h; U3l[row][col] = (__bf16)(v - (float)h);
        }
    __syncthreads();
    if (j <= 7) {
        stage_split_T(B, tid, oth, otl);
        __syncthreads();
        mm_core(w, fr, fq, U3h, U3l, oth, otl, accs);    // G_j = E @ B
#pragma unroll
        for (int mt = 0; mt < 4; ++mt)
#pragma unroll
            for (int r = 0; r < 4; ++r) {
                int row = mt * 16 + fq * 4 + r, col = w * 16 + fr;
                __bf16 hv = (__bf16)accs[mt][r];
                for (int i2 = 0; i2 + j < 8; ++i2)
                    Tfrag[TIDX(i2 * 64 + col, (i2 + j) * 64 + row)] = hv;
            }
        mm_core(w, fr, fq, curh, curl, oth, otl, accs);  // W = A^j @ B
#pragma unroll
        for (int mt = 0; mt < 4; ++mt)
#pragma unroll
            for (int r = 0; r < 4; ++r) {
                int row = mt * 16 + fq * 4 + r, col = w * 16 + fr;
                Wfrag[WIDX((7 - j) * 64 + col, row)] = (__bf16)accs[mt][r];
            }
    }
}

// ---------------- k_gemm1: f_c = W @ x_vec (chunk-final local states) ------
__global__ __launch_bounds__(64) void k_gemm1(const float* __restrict__ x,
        const __bf16* __restrict__ Wfrag, float* __restrict__ fbuf) {
    __shared__ __bf16 LA[32][64][8];
    int lane = threadIdx.x;
    int c = blockIdx.x >> 2, bg = blockIdx.x & 3;
#pragma unroll 4
    for (int it = 0; it < 64; ++it) {
        int q = lane + 64 * it;
        int dq = (q & 15) * 4, b = (q >> 4) & 31, t2 = q >> 9;
        f32x4 v = *(const f32x4*)(x + ((long)(bg * 32 + b) * T_SEQ + c * 8 + t2) * 64 + dq);
        int k = t2 * 64 + dq;
        __bf16* d = &LA[k >> 4][((k >> 3) & 1) * 32 + b][k & 7];
        d[0] = (__bf16)v[0]; d[1] = (__bf16)v[1];
        d[2] = (__bf16)v[2]; d[3] = (__bf16)v[3];
    }
    __syncthreads();
    int bcol = lane & 31, hl = lane >> 5;
    f32x16 a0 = z16(), a1 = z16();
    for (int kt = 0; kt < 32; ++kt) {
        bf16x8 a = *(const bf16x8*)&LA[kt][lane][0];
        a0 = MFMA32(a, *(const bf16x8*)(Wfrag + (((long)kt * 64 + lane) << 3)), a0);
        a1 = MFMA32(a, *(const bf16x8*)(Wfrag + (((long)(32 + kt) * 64 + lane) << 3)), a1);
    }
    float* fp = fbuf + ((long)c * 128 + bg * 32) * 64;
#pragma unroll
    for (int r = 0; r < 16; ++r) {
        int row = (r & 3) + 8 * (r >> 2) + 4 * hl;
        fp[(long)row * 64 + bcol] = a0[r];
        fp[(long)row * 64 + 32 + bcol] = a1[r];
    }
}

// ---------------- boundary scans (round-9/10 proven) -----------------------
__global__ __launch_bounds__(256) void k_bound1(const float* __restrict__ P,
        const float* __restrict__ fbuf, float* __restrict__ Fsup, int nper) {
    int wid = blockIdx.x * 4 + (threadIdx.x >> 6);
    int lane = threadIdx.x & 63;
    int s = wid >> 7, batch = wid & 127;
    float Pr[64];
    const f32x4* P4 = (const f32x4*)(P + lane * 64);
#pragma unroll
    for (int qq = 0; qq < 16; ++qq) {
        f32x4 v = P4[qq];
        Pr[qq*4] = v[0]; Pr[qq*4+1] = v[1]; Pr[qq*4+2] = v[2]; Pr[qq*4+3] = v[3];
    }
    float S = 0.f;
    for (int i = 0; i < nper; ++i) {
        int c = s * nper + i;
        float fv = fbuf[((long)c * 128 + batch) * 64 + lane];
        float a0 = fv, a1 = 0.f;
#pragma unroll
        for (int m = 0; m < 64; m += 2) {
            a0 = fmaf(Pr[m],     bcast(S, m),     a0);
            a1 = fmaf(Pr[m + 1], bcast(S, m + 1), a1);
        }
        S = a0 + a1;
    }
    Fsup[((long)s * 128 + batch) * 64 + lane] = S;
}

__global__ __launch_bounds__(256) void k_bsuper(const float* __restrict__ P,
        float* __restrict__ Fsup, int nsup) {
    int batch = blockIdx.x * 4 + (threadIdx.x >> 6);
    int lane = threadIdx.x & 63;
    float Pr[64];
    const f32x4* P4 = (const f32x4*)(P + lane * 64);
#pragma unroll
    for (int qq = 0; qq < 16; ++qq) {
        f32x4 v = P4[qq];
        Pr[qq*4] = v[0]; Pr[qq*4+1] = v[1]; Pr[qq*4+2] = v[2]; Pr[qq*4+3] = v[3];
    }
    float E = 0.f;
    for (int s = 0; s < nsup; ++s) {
        long idx = ((long)s * 128 + batch) * 64 + lane;
        float tmp = Fsup[idx];
        Fsup[idx] = E;
        float a0 = tmp, a1 = 0.f;
#pragma unroll
        for (int m = 0; m < 64; m += 2) {
            a0 = fmaf(Pr[m],     bcast(E, m),     a0);
            a1 = fmaf(Pr[m + 1], bcast(E, m + 1), a1);
        }
        E = a0 + a1;
    }
}

__global__ __launch_bounds__(256) void k_bound2(const float* __restrict__ P,
        const float* __restrict__ Fsup, float* __restrict__ fbuf, int nper) {
    int wid = blockIdx.x * 4 + (threadIdx.x >> 6);
    int lane = threadIdx.x & 63;
    int s = wid >> 7, batch = wid & 127;
    float Pr[64];
    const f32x4* P4 = (const f32x4*)(P + lane * 64);
#pragma unroll
    for (int qq = 0; qq < 16; ++qq) {
        f32x4 v = P4[qq];
        Pr[qq*4] = v[0]; Pr[qq*4+1] = v[1]; Pr[qq*4+2] = v[2]; Pr[qq*4+3] = v[3];
    }
    float S = Fsup[((long)s * 128 + batch) * 64 + lane];
    for (int i = 0; i < nper; ++i) {
        int c = s * nper + i;
        long idx = ((long)c * 128 + batch) * 64 + lane;
        float tmp = fbuf[idx];
        fbuf[idx] = S;                 // entry state of chunk c
        float a0 = tmp, a1 = 0.f;
#pragma unroll
        for (int m = 0; m < 64; m += 2) {
            a0 = fmaf(Pr[m],     bcast(S, m),     a0);
            a1 = fmaf(Pr[m + 1], bcast(S, m + 1), a1);
        }
        S = a0 + a1;
    }
}

// ---------------- k_gemm2: Y^T = X^T @ T  (+ S-extension) ------------------
// WG = (chunk c, batch-group bg of 32). 4 waves; wave wq = (w+c)&3 owns
// N-cols [wq*128, wq*128+128) = ntiles wq*4 .. wq*4+3.
// Triangular skip: tiles 0,1 (step 2wq) need kt < 8wq+4; tiles 2,3 < 8wq+8;
// S-ext kt 32..39 always.  Table loads: coalesced 1024B (Tfrag layout).
__global__ __launch_bounds__(256) void k_gemm2(const float* __restrict__ x,
        const float* __restrict__ Sbuf, const __bf16* __restrict__ Tfrag,
        float* __restrict__ y) {
    __shared__ __bf16 LA[40][64][8];
    int tid = threadIdx.x;
    int c = blockIdx.x >> 2, bg = blockIdx.x & 3;
    {   // stage X (8 t x 64 d x 32 b), A-frag order
        int dq = (tid & 15) * 4;
        int b0 = tid >> 4;
#pragma unroll
        for (int t2 = 0; t2 < 8; ++t2)
#pragma unroll
            for (int rep = 0; rep < 2; ++rep) {
                int b = b0 + rep * 16;
                f32x4 v = *(const f32x4*)(x + ((long)(bg * 32 + b) * T_SEQ + c * 8 + t2) * 64 + dq);
                int k = t2 * 64 + dq;
                __bf16* d = &LA[k >> 4][((k >> 3) & 1) * 32 + b][k & 7];
                d[0] = (__bf16)v[0]; d[1] = (__bf16)v[1];
                d[2] = (__bf16)v[2]; d[3] = (__bf16)v[3];
            }
    }
    {   // stage S hi/lo (k 512..639)
        int b = tid >> 3, d0 = (tid & 7) * 8;
        const float* sp = Sbuf + ((long)c * 128 + bg * 32 + b) * 64 + d0;
        f32x4 s0 = *(const f32x4*)sp, s1 = *(const f32x4*)(sp + 4);
        bf16x8 hi, lo;
        split8(s0, s1, hi, lo);
        int kh = 512 + d0, kl = 576 + d0;
        *(bf16x8*)&LA[kh >> 4][((kh >> 3) & 1) * 32 + b][0] = hi;
        *(bf16x8*)&LA[kl >> 4][((kl >> 3) & 1) * 32 + b][0] = lo;
    }
    __syncthreads();
    int w = tid >> 6, lane = tid & 63;
    int bcol = lane & 31, hl = lane >> 5;
    int wq = (w + c) & 3;
    // Tfrag base for this wave's 4 ntiles (wq*4 + j), per-lane 16B:
    const __bf16* tb = Tfrag + (((long)(wq * 4) * 40 + 0) * 64 + lane) * 8;
    // per-ntile stride = 40*64*8 = 20480 elems; per-kt stride = 64*8 = 512.
    f32x16 acc[4] = {z16(), z16(), z16(), z16()};
    int k1 = 8 * wq + 4, k2 = k1 + 4;
    int kt = 0;
    for (; kt < k1; ++kt) {             // all 4 tiles active
        bf16x8 a = *(const bf16x8*)&LA[kt][lane][0];
        acc[0] = MFMA32(a, *(const bf16x8*)(tb + (long)kt * 512), acc[0]);
        acc[1] = MFMA32(a, *(const bf16x8*)(tb + 20480l + (long)kt * 512), acc[1]);
        acc[2] = MFMA32(a, *(const bf16x8*)(tb + 40960l + (long)kt * 512), acc[2]);
        acc[3] = MFMA32(a, *(const bf16x8*)(tb + 61440l + (long)kt * 512), acc[3]);
    }
    for (; kt < k2; ++kt) {             // only second-step tiles (j=2,3)
        bf16x8 a = *(const bf16x8*)&LA[kt][lane][0];
        acc[2] = MFMA32(a, *(const bf16x8*)(tb + 40960l + (long)kt * 512), acc[2]);
        acc[3] = MFMA32(a, *(const bf16x8*)(tb + 61440l + (long)kt * 512), acc[3]);
    }
    for (kt = 32; kt < 40; ++kt) {      // S extension, all tiles
        bf16x8 a = *(const bf16x8*)&LA[kt][lane][0];
        acc[0] = MFMA32(a, *(const bf16x8*)(tb + (long)kt * 512), acc[0]);
        acc[1] = MFMA32(a, *(const bf16x8*)(tb + 20480l + (long)kt * 512), acc[1]);
        acc[2] = MFMA32(a, *(const bf16x8*)(tb + 40960l + (long)kt * 512), acc[2]);
        acc[3] = MFMA32(a, *(const bf16x8*)(tb + 61440l + (long)kt * 512), acc[3]);
    }
    // store: coalesced (lanes 0..31 -> 32 consecutive o of one batch row)
    long ybase = (long)(bg * 32) * 131072 + (long)c * 8 * 64;
#pragma unroll
    for (int j = 0; j < 4; ++j) {
        int s = 2 * wq + (j >> 1), ob = 32 * (j & 1);
        float* yp = y + ybase + s * 64 + ob + bcol;
#pragma unroll
        for (int r = 0; r < 16; ++r) {
            int row = (r & 3) + 8 * (r >> 2) + 4 * hl;
            yp[(long)row * 131072] = acc[j][r];
        }
    }
}

extern "C" void kernel_launch(void* const* d_in, const int* in_sizes, int n_in,
                              void* d_out, int out_size, void* d_ws, size_t ws_size,
                              hipStream_t stream) {
    const float* x = (const float*)d_in[0];
    const float* A = (const float*)d_in[1];
    const float* B = (const float*)d_in[2];
    const float* C = (const float*)d_in[3];
    const float* Dm = (const float*)d_in[4];
    float* y = (float*)d_out;
    char* ws = (char*)d_ws;

    __bf16* Tfrag = (__bf16*)(ws);                // 512*640*2 = 655,360
    __bf16* Wfrag = (__bf16*)(ws + 655360);       // 64*512*2 = 65,536
    float*  P8    = (float*)(ws + 720896);        // 16,384
    float*  P128  = (float*)(ws + 737280);        // 16,384
    float*  Fsup  = (float*)(ws + 753664);        // 16*128*64*4 = 524,288
    float*  fbuf  = (float*)(ws + 1277952);       // 256*128*64*4 = 8,388,608
    // total 9,666,560 B

    k_zero<<<160, 256, 0, stream>>>((float*)Tfrag);
    k_prep<<<10, 256, 0, stream>>>(A, B, C, Dm, P8, P128, Tfrag, Wfrag);
    k_gemm1<<<1024, 64, 0, stream>>>(x, Wfrag, fbuf);
    k_bound1<<<512, 256, 0, stream>>>(P8, fbuf, Fsup, 16);
    k_bsuper<<<32, 256, 0, stream>>>(P128, Fsup, 16);
    k_bound2<<<512, 256, 0, stream>>>(P8, Fsup, fbuf, 16);
    k_gemm2<<<1024, 256, 0, stream>>>(x, fbuf, Tfrag, y);
}

// Round 18
// 97.356 us; speedup vs baseline: 1.5346x; 1.3686x over previous
//
#include <hip/hip_runtime.h>

// SSM: h_t = A h_{t-1} + B x_t ; y_t = C h_t + D x_t
// BATCH=128, T=2048, N=64, f32. A symmetric -> transposed state:
//   G = h^T (64 x 32batch): G_t = A*G_{t-1} + B*x_t^T
// 32x32x16 MFMA tiles, 32 batches/wave, NO LDS in scans; state feedback via
// __builtin_amdgcn_permlane32_swap (round-9 proven). A split hi/lo (3-mult).
// Round 16: LCH 16->8, NCH 128->256. Round 9 ran 512 waves on 1024 SIMDs
// (half idle, Occ 4.7%); 1024 waves fills every SIMD and halves each wave's
// serial chain. Boundary = 16 supers x 16 chunks w/ P8+P128 (proven round 10).

#define T_SEQ 2048
#define LCH 8
#define NCH 256
#define NSUP 16

typedef __bf16 bf16x8 __attribute__((ext_vector_type(8)));
typedef float f32x4 __attribute__((ext_vector_type(4)));
typedef float f32x16 __attribute__((ext_vector_type(16)));
typedef unsigned int u32;
typedef unsigned int u32x2 __attribute__((ext_vector_type(2)));

#define MFMA32(a, b, c) __builtin_amdgcn_mfma_f32_32x32x16_bf16(a, b, c, 0, 0, 0)
#define MFMA16(a, b, c) __builtin_amdgcn_mfma_f32_16x16x32_bf16(a, b, c, 0, 0, 0)

__device__ __forceinline__ float bcast(float v, int l) {
    return __int_as_float(__builtin_amdgcn_readlane(__float_as_int(v), l));
}
__device__ __forceinline__ u32 pk2f(float a, float b) {
    union { __bf16 h[2]; u32 u; } z;
    z.h[0] = (__bf16)a; z.h[1] = (__bf16)b; return z.u;
}
__device__ __forceinline__ u32 pk2h(__bf16 a, __bf16 b) {
    union { __bf16 h[2]; u32 u; } z;
    z.h[0] = a; z.h[1] = b; return z.u;
}
__device__ __forceinline__ bf16x8 mk8(u32 a, u32 b, u32 c, u32 d) {
    union { u32 u[4]; bf16x8 v; } z;
    z.u[0] = a; z.u[1] = b; z.u[2] = c; z.u[3] = d; return z.v;
}
__device__ __forceinline__ void plswap(u32& a, u32& b) {
    u32x2 r = __builtin_amdgcn_permlane32_swap(a, b, false, false);
    a = r[0]; b = r[1];
}
__device__ __forceinline__ f32x16 z16() {
    f32x16 z;
#pragma unroll
    for (int e = 0; e < 16; ++e) z[e] = 0.f;
    return z;
}
__device__ __forceinline__ void split8(f32x4 a, f32x4 b, bf16x8& hi, bf16x8& lo) {
#pragma unroll
    for (int i = 0; i < 4; ++i) {
        float v = a[i]; __bf16 h = (__bf16)v; hi[i] = h; lo[i] = (__bf16)(v - (float)h);
        v = b[i]; h = (__bf16)v; hi[4 + i] = h; lo[4 + i] = (__bf16)(v - (float)h);
    }
}

// C/D tile (f32x16) -> B-operand frags (kc=0,1) hi+lo, via permlane swaps.
__device__ __forceinline__ void feedback(const f32x16& ac,
        bf16x8& gh0, bf16x8& gl0, bf16x8& gh1, bf16x8& gl1) {
    __bf16 hb[16]; float lo[16];
#pragma unroll
    for (int e = 0; e < 16; ++e) { hb[e] = (__bf16)ac[e]; lo[e] = ac[e] - (float)hb[e]; }
    u32 a0 = pk2h(hb[0], hb[1]),  a1 = pk2h(hb[2], hb[3]);
    u32 b0 = pk2h(hb[4], hb[5]),  b1 = pk2h(hb[6], hb[7]);
    u32 c0 = pk2h(hb[8], hb[9]),  c1 = pk2h(hb[10], hb[11]);
    u32 d0 = pk2h(hb[12], hb[13]), d1 = pk2h(hb[14], hb[15]);
    plswap(a0, b0); plswap(a1, b1);
    gh0 = mk8(a0, a1, b0, b1);
    plswap(c0, d0); plswap(c1, d1);
    gh1 = mk8(c0, c1, d0, d1);
    u32 e0 = pk2f(lo[0], lo[1]),  e1 = pk2f(lo[2], lo[3]);
    u32 f0 = pk2f(lo[4], lo[5]),  f1 = pk2f(lo[6], lo[7]);
    u32 g0 = pk2f(lo[8], lo[9]),  g1 = pk2f(lo[10], lo[11]);
    u32 h0 = pk2f(lo[12], lo[13]), h1 = pk2f(lo[14], lo[15]);
    plswap(e0, f0); plswap(e1, f1);
    gl0 = mk8(e0, e1, f0, f1);
    plswap(g0, h0); plswap(g1, h1);
    gl1 = mk8(g0, g1, h0, h1);
}

// ---------------- k_prep (16x16 split-MFMA squarings; proven) --------------
__device__ __forceinline__ void mmstep(int w, int fr, int fq,
        const __bf16 (*Xh)[72], const __bf16 (*Xl)[72],
        const __bf16 (*Yh)[72], const __bf16 (*Yl)[72],
        __bf16 (*Dh)[72], __bf16 (*Dl)[72]) {
    f32x4 accs[4];
#pragma unroll
    for (int mt = 0; mt < 4; ++mt) {
        f32x4 acc = {0.f, 0.f, 0.f, 0.f};
#pragma unroll
        for (int kk = 0; kk < 2; ++kk) {
            bf16x8 xh = *(const bf16x8*)&Xh[mt * 16 + fr][fq * 8 + kk * 32];
            bf16x8 xl = *(const bf16x8*)&Xl[mt * 16 + fr][fq * 8 + kk * 32];
            bf16x8 yh = *(const bf16x8*)&Yh[w * 16 + fr][fq * 8 + kk * 32];
            bf16x8 yl = *(const bf16x8*)&Yl[w * 16 + fr][fq * 8 + kk * 32];
            acc = MFMA16(xh, yh, acc);
            acc = MFMA16(xh, yl, acc);
            acc = MFMA16(xl, yh, acc);
        }
        accs[mt] = acc;
    }
    __syncthreads();
#pragma unroll
    for (int mt = 0; mt < 4; ++mt)
#pragma unroll
        for (int r = 0; r < 4; ++r) {
            float v = accs[mt][r]; __bf16 h = (__bf16)v;
            Dh[mt * 16 + fq * 4 + r][w * 16 + fr] = h;
            Dl[mt * 16 + fq * 4 + r][w * 16 + fr] = (__bf16)(v - (float)h);
        }
    __syncthreads();
}

__global__ __launch_bounds__(256) void k_prep(const float* __restrict__ A,
        const float* __restrict__ B, const float* __restrict__ C,
        const float* __restrict__ D, float* __restrict__ P8,
        float* __restrict__ P128,
        __bf16* __restrict__ A_hi, __bf16* __restrict__ A_lo,
        __bf16* __restrict__ B_bf, __bf16* __restrict__ C_bf,
        __bf16* __restrict__ D_bf) {
    if (blockIdx.x == 1) {
        for (int i = threadIdx.x; i < 4096; i += 256) {
            float a = A[i]; __bf16 h = (__bf16)a;
            A_hi[i] = h; A_lo[i] = (__bf16)(a - (float)h);
            B_bf[i] = (__bf16)B[i];
            C_bf[i] = (__bf16)C[i];
            D_bf[i] = (__bf16)D[i];
        }
        return;
    }
    __shared__ __align__(16) __bf16 X1h[64][72], X1l[64][72];
    __shared__ __align__(16) __bf16 X2h[64][72], X2l[64][72];
    int w = threadIdx.x >> 6, lane = threadIdx.x & 63;
    int fr = lane & 15, fq = lane >> 4;
    for (int i = threadIdx.x; i < 4096; i += 256) {
        int r = i >> 6, cc = i & 63;
        float a = A[i]; __bf16 h = (__bf16)a;
        X1h[r][cc] = h; X1l[r][cc] = (__bf16)(a - (float)h);
    }
    __syncthreads();
    __bf16 (*curh)[72] = X1h, (*curl)[72] = X1l;
    __bf16 (*oth)[72] = X2h, (*otl)[72] = X2l;
    for (int sq = 0; sq < 7; ++sq) {   // A^2,4,8,16,32,64,128
        mmstep(w, fr, fq, curh, curl, curh, curl, oth, otl);
        { __bf16 (*t1)[72] = curh; curh = oth; oth = t1;
          __bf16 (*t2)[72] = curl; curl = otl; otl = t2; }
        if (sq == 2) {                 // A^8
            for (int i = threadIdx.x; i < 4096; i += 256)
                P8[i] = (float)curh[i >> 6][i & 63] + (float)curl[i >> 6][i & 63];
        }
    }
    for (int i = threadIdx.x; i < 4096; i += 256)
        P128[i] = (float)curh[i >> 6][i & 63] + (float)curl[i >> 6][i & 63];
}

// ---------------- scan core (32x32 tiles, LDS-free; round-9 proven) --------
// Layouts (mfma_f32_32x32x16_bf16):
//   A-op: lane l -> M[row=l&31][k=8*(l>>5)+e (+16kc)]
//   B-op: lane l -> M[k=8*(l>>5)+e (+16kc)][col=l&31]
//   C/D : lane l -> D[row=(r&3)+8*(r>>2)+4*(l>>5)][col=l&31]
template<bool DOY>
__device__ __forceinline__ void scan_core(const float* __restrict__ x,
        const float* __restrict__ Sbuf,
        const __bf16* __restrict__ A_hi, const __bf16* __restrict__ A_lo,
        const __bf16* __restrict__ B_bf, const __bf16* __restrict__ C_bf,
        const __bf16* __restrict__ D_bf,
        float* __restrict__ fbuf, float* __restrict__ y) {
    int lane = threadIdx.x & 63;
    int bcol = lane & 31;
    int hl = lane >> 5;
    int wid = blockIdx.x;
    int g = wid >> 8;            // batch group 0..3
    int c = wid & 255;           // chunk 0..255
    int t0 = c * LCH;
    long brow = (long)(g * 32 + bcol);

    bf16x8 Afh[2][2][2], Afl[2][2][2], Bf[2][2][2], Cf[2][2][2], Df[2][2][2];
#pragma unroll
    for (int i = 0; i < 2; ++i)
#pragma unroll
        for (int j = 0; j < 2; ++j)
#pragma unroll
            for (int kc = 0; kc < 2; ++kc) {
                int off = (32 * i + bcol) * 64 + 32 * j + 16 * kc + 8 * hl;
                Afh[i][j][kc] = *(const bf16x8*)(A_hi + off);
                Afl[i][j][kc] = *(const bf16x8*)(A_lo + off);
                Bf[i][j][kc]  = *(const bf16x8*)(B_bf + off);
                if (DOY) {
                    Cf[i][j][kc] = *(const bf16x8*)(C_bf + off);
                    Df[i][j][kc] = *(const bf16x8*)(D_bf + off);
                }
            }

    bf16x8 Gh[2][2], Gl[2][2];
    if (DOY) {
        const float* Sp = Sbuf + ((long)c * 128 + brow) * 64;
#pragma unroll
        for (int jr = 0; jr < 2; ++jr)
#pragma unroll
            for (int kc = 0; kc < 2; ++kc) {
                int n0 = 32 * jr + 16 * kc + 8 * hl;
                f32x4 s0 = *(const f32x4*)(Sp + n0);
                f32x4 s1 = *(const f32x4*)(Sp + n0 + 4);
                split8(s0, s1, Gh[jr][kc], Gl[jr][kc]);
            }
    } else {
#pragma unroll
        for (int jr = 0; jr < 2; ++jr)
#pragma unroll
            for (int kc = 0; kc < 2; ++kc) {
                Gh[jr][kc] = (bf16x8)(__bf16)0.f;
                Gl[jr][kc] = (bf16x8)(__bf16)0.f;
            }
    }

    const float* xb = x + (brow * T_SEQ + t0) * 64 + 8 * hl;
    f32x4 XF[8]; bf16x8 XB[2][2];
#define LOADX(dt) { const float* p = xb + (long)(dt) * 64;                     \
    XF[0] = *(const f32x4*)(p);      XF[1] = *(const f32x4*)(p + 4);           \
    XF[2] = *(const f32x4*)(p + 16); XF[3] = *(const f32x4*)(p + 20);          \
    XF[4] = *(const f32x4*)(p + 32); XF[5] = *(const f32x4*)(p + 36);          \
    XF[6] = *(const f32x4*)(p + 48); XF[7] = *(const f32x4*)(p + 52); }
#define CVTX() {                                                               \
    XB[0][0] = mk8(pk2f(XF[0][0], XF[0][1]), pk2f(XF[0][2], XF[0][3]),         \
                   pk2f(XF[1][0], XF[1][1]), pk2f(XF[1][2], XF[1][3]));        \
    XB[0][1] = mk8(pk2f(XF[2][0], XF[2][1]), pk2f(XF[2][2], XF[2][3]),         \
                   pk2f(XF[3][0], XF[3][1]), pk2f(XF[3][2], XF[3][3]));        \
    XB[1][0] = mk8(pk2f(XF[4][0], XF[4][1]), pk2f(XF[4][2], XF[4][3]),         \
                   pk2f(XF[5][0], XF[5][1]), pk2f(XF[5][2], XF[5][3]));        \
    XB[1][1] = mk8(pk2f(XF[6][0], XF[6][1]), pk2f(XF[6][2], XF[6][3]),         \
                   pk2f(XF[7][0], XF[7][1]), pk2f(XF[7][2], XF[7][3])); }

    LOADX(0); CVTX(); LOADX(1);

    float* yb = DOY ? (y + brow * T_SEQ * 64) : nullptr;
    f32x16 ac0, ac1;
#pragma unroll
    for (int st = 0; st < LCH; ++st) {
        // u = B * x^T into fresh accumulators
        ac0 = z16(); ac1 = z16();
#pragma unroll
        for (int j = 0; j < 2; ++j)
#pragma unroll
            for (int kc = 0; kc < 2; ++kc) {
                ac0 = MFMA32(Bf[0][j][kc], XB[j][kc], ac0);
                ac1 = MFMA32(Bf[1][j][kc], XB[j][kc], ac1);
            }
        // + A * G  (3-mult split)
#pragma unroll
        for (int jr = 0; jr < 2; ++jr)
#pragma unroll
            for (int kc = 0; kc < 2; ++kc) {
                ac0 = MFMA32(Afh[0][jr][kc], Gh[jr][kc], ac0);
                ac0 = MFMA32(Afh[0][jr][kc], Gl[jr][kc], ac0);
                ac0 = MFMA32(Afl[0][jr][kc], Gh[jr][kc], ac0);
                ac1 = MFMA32(Afh[1][jr][kc], Gh[jr][kc], ac1);
                ac1 = MFMA32(Afh[1][jr][kc], Gl[jr][kc], ac1);
                ac1 = MFMA32(Afl[1][jr][kc], Gh[jr][kc], ac1);
            }
        // feedback: new G frags via permlane swaps (no LDS)
        feedback(ac0, Gh[0][0], Gl[0][0], Gh[0][1], Gl[0][1]);
        feedback(ac1, Gh[1][0], Gl[1][0], Gh[1][1], Gl[1][1]);
        if (DOY) {
            float* yp = yb + (long)(t0 + st) * 64;
#pragma unroll
            for (int i = 0; i < 2; ++i) {
                f32x16 ya = z16();
#pragma unroll
                for (int jr = 0; jr < 2; ++jr)
#pragma unroll
                    for (int kc = 0; kc < 2; ++kc) {
                        ya = MFMA32(Cf[i][jr][kc], Gh[jr][kc], ya);
                        ya = MFMA32(Cf[i][jr][kc], Gl[jr][kc], ya);
                        ya = MFMA32(Df[i][jr][kc], XB[jr][kc], ya);
                    }
#pragma unroll
                for (int m = 0; m < 4; ++m) {
                    f32x4 v;
                    v[0] = ya[4 * m]; v[1] = ya[4 * m + 1];
                    v[2] = ya[4 * m + 2]; v[3] = ya[4 * m + 3];
                    *(f32x4*)(yp + 32 * i + 8 * m + 4 * hl) = v;
                }
            }
        }
        if (!DOY && st == LCH - 1) {
            float* fp = fbuf + ((long)c * 128 + brow) * 64;
#pragma unroll
            for (int m = 0; m < 4; ++m) {
                f32x4 v0, v1;
                v0[0] = ac0[4 * m]; v0[1] = ac0[4 * m + 1];
                v0[2] = ac0[4 * m + 2]; v0[3] = ac0[4 * m + 3];
                v1[0] = ac1[4 * m]; v1[1] = ac1[4 * m + 1];
                v1[2] = ac1[4 * m + 2]; v1[3] = ac1[4 * m + 3];
                *(f32x4*)(fp + 8 * m + 4 * hl) = v0;
                *(f32x4*)(fp + 32 + 8 * m + 4 * hl) = v1;
            }
        }
        // rotate x: XB <- XF(t+1); prefetch XF(t+2) (clamped)
        CVTX();
        int nt = st + 2;
        if (t0 + nt > T_SEQ - 1) nt = T_SEQ - 1 - t0;
        LOADX(nt);
    }
#undef LOADX
#undef CVTX
}

__global__ __launch_bounds__(64, 1) void k_scan1(const float* __restrict__ x,
        const __bf16* __restrict__ A_hi, const __bf16* __restrict__ A_lo,
        const __bf16* __restrict__ B_bf, float* __restrict__ fbuf) {
    scan_core<false>(x, nullptr, A_hi, A_lo, B_bf, nullptr, nullptr, fbuf, nullptr);
}

__global__ __launch_bounds__(64, 1) void k_scan2(const float* __restrict__ x,
        const float* __restrict__ Sbuf,
        const __bf16* __restrict__ A_hi, const __bf16* __restrict__ A_lo,
        const __bf16* __restrict__ B_bf, const __bf16* __restrict__ C_bf,
        const __bf16* __restrict__ D_bf, float* __restrict__ y) {
    scan_core<true>(x, Sbuf, A_hi, A_lo, B_bf, C_bf, D_bf, nullptr, y);
}

// ---------------- boundary scans (runtime-parameterized; round-10 proven) --
__global__ __launch_bounds__(256) void k_bound1(const float* __restrict__ P,
        const float* __restrict__ fbuf, float* __restrict__ Fsup, int nper) {
    int wid = blockIdx.x * 4 + (threadIdx.x >> 6);
    int lane = threadIdx.x & 63;
    int s = wid >> 7, batch = wid & 127;
    float Pr[64];
    const f32x4* P4 = (const f32x4*)(P + lane * 64);
#pragma unroll
    for (int qq = 0; qq < 16; ++qq) {
        f32x4 v = P4[qq];
        Pr[qq*4] = v[0]; Pr[qq*4+1] = v[1]; Pr[qq*4+2] = v[2]; Pr[qq*4+3] = v[3];
    }
    float S = 0.f;
    for (int i = 0; i < nper; ++i) {
        int c = s * nper + i;
        float fv = fbuf[((long)c * 128 + batch) * 64 + lane];
        float a0 = fv, a1 = 0.f;
#pragma unroll
        for (int m = 0; m < 64; m += 2) {
            a0 = fmaf(Pr[m],     bcast(S, m),     a0);
            a1 = fmaf(Pr[m + 1], bcast(S, m + 1), a1);
        }
        S = a0 + a1;
    }
    Fsup[((long)s * 128 + batch) * 64 + lane] = S;
}

__global__ __launch_bounds__(256) void k_bsuper(const float* __restrict__ P,
        float* __restrict__ Fsup, int nsup) {
    int batch = blockIdx.x * 4 + (threadIdx.x >> 6);
    int lane = threadIdx.x & 63;
    float Pr[64];
    const f32x4* P4 = (const f32x4*)(P + lane * 64);
#pragma unroll
    for (int qq = 0; qq < 16; ++qq) {
        f32x4 v = P4[qq];
        Pr[qq*4] = v[0]; Pr[qq*4+1] = v[1]; Pr[qq*4+2] = v[2]; Pr[qq*4+3] = v[3];
    }
    float E = 0.f;
    for (int s = 0; s < nsup; ++s) {
        long idx = ((long)s * 128 + batch) * 64 + lane;
        float tmp = Fsup[idx];
        Fsup[idx] = E;
        float a0 = tmp, a1 = 0.f;
#pragma unroll
        for (int m = 0; m < 64; m += 2) {
            a0 = fmaf(Pr[m],     bcast(E, m),     a0);
            a1 = fmaf(Pr[m + 1], bcast(E, m + 1), a1);
        }
        E = a0 + a1;
    }
}

__global__ __launch_bounds__(256) void k_bound2(const float* __restrict__ P,
        const float* __restrict__ Fsup, float* __restrict__ fbuf, int nper) {
    int wid = blockIdx.x * 4 + (threadIdx.x >> 6);
    int lane = threadIdx.x & 63;
    int s = wid >> 7, batch = wid & 127;
    float Pr[64];
    const f32x4* P4 = (const f32x4*)(P + lane * 64);
#pragma unroll
    for (int qq = 0; qq < 16; ++qq) {
        f32x4 v = P4[qq];
        Pr[qq*4] = v[0]; Pr[qq*4+1] = v[1]; Pr[qq*4+2] = v[2]; Pr[qq*4+3] = v[3];
    }
    float S = Fsup[((long)s * 128 + batch) * 64 + lane];
    for (int i = 0; i < nper; ++i) {
        int c = s * nper + i;
        long idx = ((long)c * 128 + batch) * 64 + lane;
        float tmp = fbuf[idx];
        fbuf[idx] = S;                 // entry state of chunk c
        float a0 = tmp, a1 = 0.f;
#pragma unroll
        for (int m = 0; m < 64; m += 2) {
            a0 = fmaf(Pr[m],     bcast(S, m),     a0);
            a1 = fmaf(Pr[m + 1], bcast(S, m + 1), a1);
        }
        S = a0 + a1;
    }
}

extern "C" void kernel_launch(void* const* d_in, const int* in_sizes, int n_in,
                              void* d_out, int out_size, void* d_ws, size_t ws_size,
                              hipStream_t stream) {
    const float* x = (const float*)d_in[0];
    const float* A = (const float*)d_in[1];
    const float* B = (const float*)d_in[2];
    const float* C = (const float*)d_in[3];
    const float* D = (const float*)d_in[4];
    float* y = (float*)d_out;
    char* ws = (char*)d_ws;

    float*  fbuf = (float*)(ws);                  // 256*128*64*4 = 8,388,608
    float*  Fsup = (float*)(ws + 8388608);        // 16*128*64*4 = 524,288
    float*  P8   = (float*)(ws + 8912896);        // 16,384
    float*  P128 = (float*)(ws + 8929280);        // 16,384
    __bf16* A_hi = (__bf16*)(ws + 8945664);       // 8,192 each
    __bf16* A_lo = (__bf16*)(ws + 8953856);
    __bf16* B_bf = (__bf16*)(ws + 8962048);
    __bf16* C_bf = (__bf16*)(ws + 8970240);
    __bf16* D_bf = (__bf16*)(ws + 8978432);
    // total 8,986,624 B (ws >= 42.6 MB proven in round 10)

    k_prep<<<2, 256, 0, stream>>>(A, B, C, D, P8, P128,
                                  A_hi, A_lo, B_bf, C_bf, D_bf);
    k_scan1<<<1024, 64, 0, stream>>>(x, A_hi, A_lo, B_bf, fbuf);
    k_bound1<<<512, 256, 0, stream>>>(P8, fbuf, Fsup, 16);
    k_bsuper<<<32, 256, 0, stream>>>(P128, Fsup, 16);
    k_bound2<<<512, 256, 0, stream>>>(P8, Fsup, fbuf, 16);
    k_scan2<<<1024, 64, 0, stream>>>(x, fbuf, A_hi, A_lo, B_bf, C_bf, D_bf, y);
}